// Round 1
// baseline (264.426 us; speedup 1.0000x reference)
//
#include <hip/hip_runtime.h>

typedef __bf16 bf16;
typedef __bf16 bf16x8 __attribute__((ext_vector_type(8)));
typedef __bf16 bf16x4 __attribute__((ext_vector_type(4)));
typedef float f32x4 __attribute__((ext_vector_type(4)));

__device__ __forceinline__ void gload_lds16(const void* g, void* l) {
  __builtin_amdgcn_global_load_lds(
      (const __attribute__((address_space(1))) void*)g,
      (__attribute__((address_space(3))) void*)l, 16, 0, 0);
}

__global__ __launch_bounds__(256) void cast_f32_bf16(const float* __restrict__ in,
                                                     bf16* __restrict__ out, int n) {
  int i = (blockIdx.x * 256 + threadIdx.x) * 4;
  if (i < n) {
    float4 v = *(const float4*)(in + i);
    bf16x4 o = {(bf16)v.x, (bf16)v.y, (bf16)v.z, (bf16)v.w};
    *(bf16x4*)(out + i) = o;
  }
}

// C = A * B^T.  A[M,K], B[N,K] bf16 row-major.
// EPI 0: write float C[M,N] to Cf.
// EPI 1: N==6144 qkv split: n<2048 -> qb[m][n], n<4096 -> kb[m][n-2048],
//        else vt[(n-4096)][m] (V transposed for attention PV).
template <int EPI>
__global__ __launch_bounds__(256) void gemm_bt(const bf16* __restrict__ A,
                                               const bf16* __restrict__ B,
                                               float* __restrict__ Cf,
                                               bf16* __restrict__ qb,
                                               bf16* __restrict__ kb,
                                               bf16* __restrict__ vt,
                                               int M, int N, int K) {
  __shared__ bf16 As[128 * 32];
  __shared__ bf16 Bs[128 * 32];
  const int t = threadIdx.x;
  const int w = t >> 6, l = t & 63;
  const int lr = l & 15, lg = l >> 4;
  const int bm = blockIdx.y, bn = blockIdx.x;
  const int wr = w >> 1, wc = w & 1;

  f32x4 acc[4][4] = {};

  const int row0 = t >> 2;          // chunk c = r*256+t: row = r*64 + (t>>2)
  const int cc0 = (t & 3) * 8;      // 8-elem column offset within the 32-wide K slab

  for (int k0 = 0; k0 < K; k0 += 32) {
#pragma unroll
    for (int r = 0; r < 2; ++r) {
      const int row = r * 64 + row0;
      gload_lds16(A + (size_t)(bm * 128 + row) * K + k0 + cc0,
                  (char*)As + (r * 256 + w * 64) * 16);
      gload_lds16(B + (size_t)(bn * 128 + row) * K + k0 + cc0,
                  (char*)Bs + (r * 256 + w * 64) * 16);
    }
    __syncthreads();
    bf16x8 af[4], bfr[4];
#pragma unroll
    for (int i = 0; i < 4; ++i) {
      af[i] = *(const bf16x8*)((const char*)As + (wr * 64 + i * 16 + lr) * 64 + lg * 16);
      bfr[i] = *(const bf16x8*)((const char*)Bs + (wc * 64 + i * 16 + lr) * 64 + lg * 16);
    }
#pragma unroll
    for (int mi = 0; mi < 4; ++mi)
#pragma unroll
      for (int ni = 0; ni < 4; ++ni)
        acc[mi][ni] = __builtin_amdgcn_mfma_f32_16x16x32_bf16(af[mi], bfr[ni],
                                                              acc[mi][ni], 0, 0, 0);
    __syncthreads();
  }

  // C/D layout: col = lane&15, row = (lane>>4)*4 + reg   [m89-verified]
  const int mb = bm * 128 + wr * 64 + lg * 4;
  const int nb = bn * 128 + wc * 64 + lr;
  if (EPI == 0) {
#pragma unroll
    for (int mi = 0; mi < 4; ++mi) {
      const int mg = mb + mi * 16;
#pragma unroll
      for (int ni = 0; ni < 4; ++ni) {
        const int ng = nb + ni * 16;
#pragma unroll
        for (int rr = 0; rr < 4; ++rr)
          Cf[(size_t)(mg + rr) * N + ng] = acc[mi][ni][rr];
      }
    }
  } else {
    if (bn * 128 < 4096) {
      bf16* dst = (bn * 128 < 2048) ? qb : kb;
#pragma unroll
      for (int mi = 0; mi < 4; ++mi) {
        const int mg = mb + mi * 16;
#pragma unroll
        for (int ni = 0; ni < 4; ++ni) {
          const int ng = (nb + ni * 16) & 2047;
#pragma unroll
          for (int rr = 0; rr < 4; ++rr)
            dst[(size_t)(mg + rr) * 2048 + ng] = (bf16)acc[mi][ni][rr];
        }
      }
    } else {
#pragma unroll
      for (int mi = 0; mi < 4; ++mi) {
        const int mg = mb + mi * 16;
#pragma unroll
        for (int ni = 0; ni < 4; ++ni) {
          const int dc = nb + ni * 16 - 4096;
          bf16x4 pk = {(bf16)acc[mi][ni][0], (bf16)acc[mi][ni][1],
                       (bf16)acc[mi][ni][2], (bf16)acc[mi][ni][3]};
          *(bf16x4*)(vt + (size_t)dc * 2048 + mg) = pk;  // 4 consecutive m, 8B store
        }
      }
    }
  }
}

// Flash attention, causal + ALiBi.  qb/kb: [S][2048] bf16 (head h at cols h*128).
// vt: [2048][S] bf16 (row = h*128 + dcol, col = seq).  out: [S][2048] bf16.
// Block: 4 waves, 64 Q-rows (16/wave). KV tile = 32.
__global__ __launch_bounds__(256) void attn_kernel(const bf16* __restrict__ qb,
                                                   const bf16* __restrict__ kb,
                                                   const bf16* __restrict__ vt,
                                                   bf16* __restrict__ out) {
  constexpr int S = 2048, D = 2048;
  __shared__ bf16 Ks[32 * 128];   // swizzled: chunk ^= (row&7)
  __shared__ bf16 Vs[128 * 32];   // swizzled: chunk ^= ((row>>1)&3)
  __shared__ bf16 Ps[4 * 16 * 32];  // per-wave P tile, chunk ^= ((row>>1)&3)
  const int t = threadIdx.x;
  const int w = t >> 6, l = t & 63;
  const int lr = l & 15, lg = l >> 4;
  const int q0 = blockIdx.x * 64;
  const int h = blockIdx.y;
  const float slope = exp2f(-0.5f * (float)(h + 1));
  const float scale = 0.08838834764831845f;  // 1/sqrt(128)

  bf16x8 qf[4];
  {
    const bf16* qrow = qb + (size_t)(q0 + w * 16 + lr) * D + h * 128 + lg * 8;
#pragma unroll
    for (int kk = 0; kk < 4; ++kk) qf[kk] = *(const bf16x8*)(qrow + kk * 32);
  }

  f32x4 ob[8] = {};
  float mrow[4] = {-1e30f, -1e30f, -1e30f, -1e30f};
  float lrow[4] = {0.f, 0.f, 0.f, 0.f};

  const int nt = q0 / 32 + 2;  // causal: tiles up to and including the diagonal
  for (int tile = 0; tile < nt; ++tile) {
    const int kv0 = tile * 32;
#pragma unroll
    for (int r = 0; r < 2; ++r) {
      const int c = r * 256 + t;
      {  // K tile [32][128]: pre-swizzled global source, linear LDS dest
        const int row = c >> 4;
        const int scc = ((c & 15) ^ (row & 7)) * 8;
        gload_lds16(kb + (size_t)(kv0 + row) * D + h * 128 + scc,
                    (char*)Ks + (r * 256 + w * 64) * 16);
      }
      {  // Vt tile [128][32]
        const int row = c >> 2;
        const int scc = ((c & 3) ^ ((row >> 1) & 3)) * 8;
        gload_lds16(vt + (size_t)(h * 128 + row) * S + kv0 + scc,
                    (char*)Vs + (r * 256 + w * 64) * 16);
      }
    }
    __syncthreads();

    // QK^T: A = Q rows, B-frag reads K rows (same per-lane pattern)
    f32x4 sc[2] = {};
#pragma unroll
    for (int jb = 0; jb < 2; ++jb) {
      const int row = jb * 16 + lr;
#pragma unroll
      for (int kk = 0; kk < 4; ++kk) {
        const int byte = (row * 256 + kk * 64 + lg * 16) ^ ((row & 7) << 4);
        bf16x8 kf = *(const bf16x8*)((const char*)Ks + byte);
        sc[jb] = __builtin_amdgcn_mfma_f32_16x16x32_bf16(qf[kk], kf, sc[jb], 0, 0, 0);
      }
    }

    // online softmax (rows live in 16-lane groups sharing lg)
    float pv[2][4];
#pragma unroll
    for (int rr = 0; rr < 4; ++rr) {
      const int i = q0 + w * 16 + lg * 4 + rr;
#pragma unroll
      for (int jb = 0; jb < 2; ++jb) {
        const int j = kv0 + jb * 16 + lr;
        const float v = sc[jb][rr] * scale - (float)(S - 1 - j) * slope;
        pv[jb][rr] = (j <= i) ? v : -1e30f;
      }
      float m2 = fmaxf(pv[0][rr], pv[1][rr]);
      m2 = fmaxf(m2, __shfl_xor(m2, 1));
      m2 = fmaxf(m2, __shfl_xor(m2, 2));
      m2 = fmaxf(m2, __shfl_xor(m2, 4));
      m2 = fmaxf(m2, __shfl_xor(m2, 8));
      const float mnew = fmaxf(mrow[rr], m2);
      const float cf = __expf(mrow[rr] - mnew);
      const float p0 = __expf(pv[0][rr] - mnew);
      const float p1 = __expf(pv[1][rr] - mnew);
      const int prow = lg * 4 + rr;
      const int sw = ((prow >> 1) & 3) << 4;
      char* pbase = (char*)Ps + w * 1024;
      *(bf16*)(pbase + ((prow * 64 + lr * 2) ^ sw)) = (bf16)p0;
      *(bf16*)(pbase + ((prow * 64 + 32 + lr * 2) ^ sw)) = (bf16)p1;
      float ps = p0 + p1;
      ps += __shfl_xor(ps, 1);
      ps += __shfl_xor(ps, 2);
      ps += __shfl_xor(ps, 4);
      ps += __shfl_xor(ps, 8);
      lrow[rr] = lrow[rr] * cf + ps;
      mrow[rr] = mnew;
#pragma unroll
      for (int db = 0; db < 8; ++db) ob[db][rr] *= cf;
    }
    __syncthreads();  // P visible (also orders in-wave ds_write -> ds_read)

    // PV: A = P (16x32), B-frag from Vt rows (= V columns)
    bf16x8 pf;
    {
      const int byte = (lr * 64 + lg * 16) ^ (((lr >> 1) & 3) << 4);
      pf = *(const bf16x8*)((const char*)Ps + w * 1024 + byte);
    }
#pragma unroll
    for (int db = 0; db < 8; ++db) {
      const int row = db * 16 + lr;
      const int byte = (row * 64 + lg * 16) ^ (((row >> 1) & 3) << 4);
      bf16x8 vf = *(const bf16x8*)((const char*)Vs + byte);
      ob[db] = __builtin_amdgcn_mfma_f32_16x16x32_bf16(pf, vf, ob[db], 0, 0, 0);
    }
    __syncthreads();  // all LDS reads done before next tile's staging
  }

#pragma unroll
  for (int rr = 0; rr < 4; ++rr) {
    const float inv = 1.0f / lrow[rr];
    const int mg = q0 + w * 16 + lg * 4 + rr;
#pragma unroll
    for (int db = 0; db < 8; ++db)
      out[(size_t)mg * D + h * 128 + db * 16 + lr] = (bf16)(ob[db][rr] * inv);
  }
}

extern "C" void kernel_launch(void* const* d_in, const int* in_sizes, int n_in,
                              void* d_out, int out_size, void* d_ws, size_t ws_size,
                              hipStream_t stream) {
  (void)in_sizes; (void)n_in; (void)out_size; (void)ws_size;
  const float* x = (const float*)d_in[0];
  const float* wqkv = (const float*)d_in[1];
  const float* wout = (const float*)d_in[2];
  float* out = (float*)d_out;

  // ws layout (64 MB total):
  bf16* x_bf = (bf16*)d_ws;                          //  8 MB
  bf16* wqkv_bf = x_bf + (size_t)2048 * 2048;        // 24 MB
  bf16* wout_bf = wqkv_bf + (size_t)6144 * 2048;     //  8 MB
  bf16* qb = wout_bf + (size_t)2048 * 2048;          //  8 MB
  bf16* kb = qb + (size_t)2048 * 2048;               //  8 MB
  bf16* vt = kb + (size_t)2048 * 2048;               //  8 MB
  bf16* attn = wqkv_bf;  // alias: wqkv_bf is dead after GEMM1 (re-cast every call)

  cast_f32_bf16<<<4096, 256, 0, stream>>>(x, x_bf, 2048 * 2048);
  cast_f32_bf16<<<12288, 256, 0, stream>>>(wqkv, wqkv_bf, 6144 * 2048);
  cast_f32_bf16<<<4096, 256, 0, stream>>>(wout, wout_bf, 2048 * 2048);

  gemm_bt<1><<<dim3(48, 16), 256, 0, stream>>>(x_bf, wqkv_bf, nullptr, qb, kb, vt,
                                               2048, 6144, 2048);
  attn_kernel<<<dim3(32, 16), 256, 0, stream>>>(qb, kb, vt, attn);
  gemm_bt<0><<<dim3(16, 16), 256, 0, stream>>>(attn, wout_bf, out, nullptr, nullptr,
                                               nullptr, 2048, 2048, 2048);
}

// Round 2
// 219.794 us; speedup vs baseline: 1.2031x; 1.2031x over previous
//
#include <hip/hip_runtime.h>

typedef __bf16 bf16;
typedef __bf16 bf16x8 __attribute__((ext_vector_type(8)));
typedef __bf16 bf16x4 __attribute__((ext_vector_type(4)));
typedef float f32x4 __attribute__((ext_vector_type(4)));

#if __has_builtin(__builtin_amdgcn_exp2f)
#define EXP2(x) __builtin_amdgcn_exp2f(x)
#else
#define EXP2(x) exp2f(x)
#endif

__device__ __forceinline__ void gload_lds16(const void* g, void* l) {
  __builtin_amdgcn_global_load_lds(
      (const __attribute__((address_space(1))) void*)g,
      (__attribute__((address_space(3))) void*)l, 16, 0, 0);
}

__global__ __launch_bounds__(256) void cast_f32_bf16(const float* __restrict__ in,
                                                     bf16* __restrict__ out, int n) {
  int i = (blockIdx.x * 256 + threadIdx.x) * 4;
  if (i < n) {
    float4 v = *(const float4*)(in + i);
    bf16x4 o = {(bf16)v.x, (bf16)v.y, (bf16)v.z, (bf16)v.w};
    *(bf16x4*)(out + i) = o;
  }
}

// C = A * B^T.  A[M,K], B[N,K] bf16 row-major.
// EPI 0: float C to Cf. EPI 1: qkv split (q/k natural, v transposed).
template <int EPI>
__global__ __launch_bounds__(256) void gemm_bt(const bf16* __restrict__ A,
                                               const bf16* __restrict__ B,
                                               float* __restrict__ Cf,
                                               bf16* __restrict__ qb,
                                               bf16* __restrict__ kb,
                                               bf16* __restrict__ vt,
                                               int M, int N, int K) {
  __shared__ bf16 As[128 * 32];
  __shared__ bf16 Bs[128 * 32];
  const int t = threadIdx.x;
  const int w = t >> 6, l = t & 63;
  const int lr = l & 15, lg = l >> 4;
  // XCD-aware bijective swizzle (nwg % 8 == 0 for both call sites)
  const int nwg = gridDim.x * gridDim.y;
  int lin = blockIdx.y * gridDim.x + blockIdx.x;
  lin = (lin & 7) * (nwg >> 3) + (lin >> 3);
  const int bn = lin % gridDim.x;
  const int bm = lin / gridDim.x;
  const int wr = w >> 1, wc = w & 1;

  f32x4 acc[4][4] = {};

  const int row0 = t >> 2;
  const int cc0 = (t & 3) * 8;

  for (int k0 = 0; k0 < K; k0 += 32) {
#pragma unroll
    for (int r = 0; r < 2; ++r) {
      const int row = r * 64 + row0;
      gload_lds16(A + (size_t)(bm * 128 + row) * K + k0 + cc0,
                  (char*)As + (r * 256 + w * 64) * 16);
      gload_lds16(B + (size_t)(bn * 128 + row) * K + k0 + cc0,
                  (char*)Bs + (r * 256 + w * 64) * 16);
    }
    __syncthreads();
    bf16x8 af[4], bfr[4];
#pragma unroll
    for (int i = 0; i < 4; ++i) {
      af[i] = *(const bf16x8*)((const char*)As + (wr * 64 + i * 16 + lr) * 64 + lg * 16);
      bfr[i] = *(const bf16x8*)((const char*)Bs + (wc * 64 + i * 16 + lr) * 64 + lg * 16);
    }
#pragma unroll
    for (int mi = 0; mi < 4; ++mi)
#pragma unroll
      for (int ni = 0; ni < 4; ++ni)
        acc[mi][ni] = __builtin_amdgcn_mfma_f32_16x16x32_bf16(af[mi], bfr[ni],
                                                              acc[mi][ni], 0, 0, 0);
    __syncthreads();
  }

  const int mb = bm * 128 + wr * 64 + lg * 4;
  const int nb = bn * 128 + wc * 64 + lr;
  if (EPI == 0) {
#pragma unroll
    for (int mi = 0; mi < 4; ++mi) {
      const int mg = mb + mi * 16;
#pragma unroll
      for (int ni = 0; ni < 4; ++ni) {
        const int ng = nb + ni * 16;
#pragma unroll
        for (int rr = 0; rr < 4; ++rr)
          Cf[(size_t)(mg + rr) * N + ng] = acc[mi][ni][rr];
      }
    }
  } else {
    if (bn * 128 < 4096) {
      bf16* dst = (bn * 128 < 2048) ? qb : kb;
#pragma unroll
      for (int mi = 0; mi < 4; ++mi) {
        const int mg = mb + mi * 16;
#pragma unroll
        for (int ni = 0; ni < 4; ++ni) {
          const int ng = (nb + ni * 16) & 2047;
#pragma unroll
          for (int rr = 0; rr < 4; ++rr)
            dst[(size_t)(mg + rr) * 2048 + ng] = (bf16)acc[mi][ni][rr];
        }
      }
    } else {
#pragma unroll
      for (int mi = 0; mi < 4; ++mi) {
        const int mg = mb + mi * 16;
#pragma unroll
        for (int ni = 0; ni < 4; ++ni) {
          const int dc = nb + ni * 16 - 4096;
          bf16x4 pk = {(bf16)acc[mi][ni][0], (bf16)acc[mi][ni][1],
                       (bf16)acc[mi][ni][2], (bf16)acc[mi][ni][3]};
          *(bf16x4*)(vt + (size_t)dc * 2048 + mg) = pk;
        }
      }
    }
  }
}

// Flash attention, causal + ALiBi, KVBLK=64, double-buffered, 1 barrier/tile.
// qb/kb: [S][2048] bf16.  vt: [2048][S] bf16 (row = h*128+d, col = seq).
// 4 waves, 64 Q rows/block (16/wave).  log2-domain softmax.
__global__ __launch_bounds__(256) void attn_kernel(const bf16* __restrict__ qb,
                                                   const bf16* __restrict__ kb,
                                                   const bf16* __restrict__ vt,
                                                   bf16* __restrict__ out) {
  constexpr int S = 2048, D = 2048;
  __shared__ bf16 Ks[2][64 * 128];  // chunk(16B) ^= row&7 within row
  __shared__ bf16 Vs[2][128 * 64];  // chunk ^= row&7 (8 chunks/row)
  __shared__ bf16 Ps[4][16 * 64];   // per-wave, byte ^= (row&7)<<4
  const int t = threadIdx.x;
  const int w = t >> 6, l = t & 63;
  const int lr = l & 15, lg = l >> 4;
  const int q0 = (int)(gridDim.x - 1 - blockIdx.x) * 64;  // heavy blocks first
  const int h = blockIdx.y;
  const float slope2 = exp2f(-0.5f * (float)(h + 1)) * 1.4426950408889634f;
  const float scale2 = 0.08838834764831845f * 1.4426950408889634f;  // /sqrt(128)*log2e

  bf16x8 qf[4];
  {
    const bf16* qrow = qb + (size_t)(q0 + w * 16 + lr) * D + h * 128 + lg * 8;
#pragma unroll
    for (int kk = 0; kk < 4; ++kk) qf[kk] = *(const bf16x8*)(qrow + kk * 32);
  }

  f32x4 ob[8] = {};
  float mrow[4] = {-1e30f, -1e30f, -1e30f, -1e30f};
  float lrow[4] = {0.f, 0.f, 0.f, 0.f};  // PER-LANE partial; reduced in epilogue

  const int nt = (q0 >> 6) + 1;

  auto stage = [&](int kv0, int b) {
#pragma unroll
    for (int r = 0; r < 4; ++r) {
      {  // K tile [64][128]: pre-swizzled source, linear LDS dest
        const int krow = r * 16 + (t >> 4);
        const int kcc = t & 15;
        gload_lds16(kb + (size_t)(kv0 + krow) * D + h * 128 + ((kcc ^ (krow & 7)) * 8),
                    (char*)Ks[b] + (r * 256 + w * 64) * 16);
      }
      {  // Vt tile [128][64]
        const int vrow = r * 32 + (t >> 3);
        const int vcc = t & 7;
        gload_lds16(vt + (size_t)(h * 128 + vrow) * S + kv0 + ((vcc ^ (vrow & 7)) * 8),
                    (char*)Vs[b] + (r * 256 + w * 64) * 16);
      }
    }
  };

  stage(0, 0);
  int cur = 0;
  for (int tile = 0; tile < nt; ++tile) {
    __syncthreads();  // drains stage(cur); prev tile's LDS reads done
    if (tile + 1 < nt) stage((tile + 1) << 6, cur ^ 1);  // in flight during compute
    const int kv0 = tile << 6;

    // QK^T
    f32x4 sc[4] = {};
#pragma unroll
    for (int jb = 0; jb < 4; ++jb) {
      const int row = jb * 16 + lr;
#pragma unroll
      for (int kk = 0; kk < 4; ++kk) {
        const int byte = row * 256 + ((kk * 64 + lg * 16) ^ ((row & 7) << 4));
        bf16x8 kf = *(const bf16x8*)((const char*)Ks[cur] + byte);
        sc[jb] = __builtin_amdgcn_mfma_f32_16x16x32_bf16(qf[kk], kf, sc[jb], 0, 0, 0);
      }
    }

    // softmax (log2 domain; scale+alibi folded into one fma)
    float bias[4];
#pragma unroll
    for (int jb = 0; jb < 4; ++jb)
      bias[jb] = slope2 * (float)(kv0 + jb * 16 + lr - (S - 1));
    const bool diag = (tile == nt - 1);
    float xv[4][4], m2r[4];
#pragma unroll
    for (int rr = 0; rr < 4; ++rr) {
#pragma unroll
      for (int jb = 0; jb < 4; ++jb) {
        float v = fmaf(sc[jb][rr], scale2, bias[jb]);
        if (diag && (jb * 16 + lr > w * 16 + lg * 4 + rr)) v = -1e30f;
        xv[rr][jb] = v;
      }
      float m2 = fmaxf(fmaxf(xv[rr][0], xv[rr][1]), fmaxf(xv[rr][2], xv[rr][3]));
      m2 = fmaxf(m2, __shfl_xor(m2, 1));
      m2 = fmaxf(m2, __shfl_xor(m2, 2));
      m2 = fmaxf(m2, __shfl_xor(m2, 4));
      m2 = fmaxf(m2, __shfl_xor(m2, 8));
      m2r[rr] = m2;
    }
    // defer-max (T13): skip O/l rescale when max growth <= 8 (log2 units)
    float need = fmaxf(fmaxf(m2r[0] - mrow[0], m2r[1] - mrow[1]),
                       fmaxf(m2r[2] - mrow[2], m2r[3] - mrow[3]));
    if (!__all(need <= 8.0f)) {
#pragma unroll
      for (int rr = 0; rr < 4; ++rr) {
        const float mnew = fmaxf(mrow[rr], m2r[rr]);
        const float cf = EXP2(mrow[rr] - mnew);
        lrow[rr] *= cf;
        mrow[rr] = mnew;
#pragma unroll
        for (int db = 0; db < 8; ++db) ob[db][rr] *= cf;
      }
    }
    char* pbase = (char*)Ps[w];
#pragma unroll
    for (int rr = 0; rr < 4; ++rr) {
      const int prow = lg * 4 + rr;
      const int sw = (prow & 7) << 4;
      float ps = 0.f;
#pragma unroll
      for (int jb = 0; jb < 4; ++jb) {
        const float p = EXP2(xv[rr][jb] - mrow[rr]);
        *(bf16*)(pbase + ((prow * 128 + jb * 32 + lr * 2) ^ sw)) = (bf16)p;
        ps += p;
      }
      lrow[rr] += ps;  // cross-lane reduce deferred to epilogue
    }

    // PV (P is per-wave: in-wave DS ordering suffices, no barrier)
    bf16x8 pf[2];
#pragma unroll
    for (int s = 0; s < 2; ++s)
      pf[s] = *(const bf16x8*)(pbase + ((lr * 128 + s * 64 + lg * 16) ^ ((lr & 7) << 4)));
#pragma unroll
    for (int db = 0; db < 8; ++db) {
      const int vrow = db * 16 + lr;
#pragma unroll
      for (int s = 0; s < 2; ++s) {
        const int byte = vrow * 128 + ((s * 64 + lg * 16) ^ ((vrow & 7) << 4));
        bf16x8 vf = *(const bf16x8*)((const char*)Vs[cur] + byte);
        ob[db] = __builtin_amdgcn_mfma_f32_16x16x32_bf16(pf[s], vf, ob[db], 0, 0, 0);
      }
    }
    cur ^= 1;
  }

#pragma unroll
  for (int rr = 0; rr < 4; ++rr) {
    float ls = lrow[rr];
    ls += __shfl_xor(ls, 1);
    ls += __shfl_xor(ls, 2);
    ls += __shfl_xor(ls, 4);
    ls += __shfl_xor(ls, 8);
    const float inv = 1.0f / ls;
    const int mg = q0 + w * 16 + lg * 4 + rr;
#pragma unroll
    for (int db = 0; db < 8; ++db)
      out[(size_t)mg * D + h * 128 + db * 16 + lr] = (bf16)(ob[db][rr] * inv);
  }
}

extern "C" void kernel_launch(void* const* d_in, const int* in_sizes, int n_in,
                              void* d_out, int out_size, void* d_ws, size_t ws_size,
                              hipStream_t stream) {
  (void)in_sizes; (void)n_in; (void)out_size; (void)ws_size;
  const float* x = (const float*)d_in[0];
  const float* wqkv = (const float*)d_in[1];
  const float* wout = (const float*)d_in[2];
  float* out = (float*)d_out;

  bf16* x_bf = (bf16*)d_ws;                          //  8 MB
  bf16* wqkv_bf = x_bf + (size_t)2048 * 2048;        // 24 MB
  bf16* wout_bf = wqkv_bf + (size_t)6144 * 2048;     //  8 MB
  bf16* qb = wout_bf + (size_t)2048 * 2048;          //  8 MB
  bf16* kb = qb + (size_t)2048 * 2048;               //  8 MB
  bf16* vt = kb + (size_t)2048 * 2048;               //  8 MB
  bf16* attn = wqkv_bf;  // wqkv_bf dead after GEMM1

  cast_f32_bf16<<<4096, 256, 0, stream>>>(x, x_bf, 2048 * 2048);
  cast_f32_bf16<<<12288, 256, 0, stream>>>(wqkv, wqkv_bf, 6144 * 2048);
  cast_f32_bf16<<<4096, 256, 0, stream>>>(wout, wout_bf, 2048 * 2048);

  gemm_bt<1><<<dim3(48, 16), 256, 0, stream>>>(x_bf, wqkv_bf, nullptr, qb, kb, vt,
                                               2048, 6144, 2048);
  attn_kernel<<<dim3(32, 16), 256, 0, stream>>>(qb, kb, vt, attn);
  gemm_bt<0><<<dim3(16, 16), 256, 0, stream>>>(attn, wout_bf, out, nullptr, nullptr,
                                               nullptr, 2048, 2048, 2048);
}